// Round 3
// baseline (366.474 us; speedup 1.0000x reference)
//
#include <hip/hip_runtime.h>
#include <hip/hip_bf16.h>
#include <cstdint>

#define ALPHA 8.3f

typedef __attribute__((ext_vector_type(8))) short bf16x8;
typedef __attribute__((ext_vector_type(4))) float f32x4;

// bf16 weights, layout [tap][o][c]  (9*128*128)
__device__ __align__(16) short g_wt[9 * 128 * 128];
// bf16 input, HWC with zero halo: [b][h'][w'][c], h',w' in [0,130)
__device__ __align__(16) short g_xt[(size_t)8 * 130 * 130 * 128];
// padded fp32 depth: [b][h'][w']
__device__ float g_dp[8 * 130 * 130];

__device__ __forceinline__ short f2bf(float f) {
    union { float f; uint32_t u; } v; v.f = f;
    uint32_t r = v.u + 0x7fffu + ((v.u >> 16) & 1u);
    return (short)(r >> 16);
}

// weight: (Cout=128, Cin=128, 3, 3) fp32  ->  g_wt[tap][o][c] bf16
__global__ __launch_bounds__(256) void wt_transform(const float* __restrict__ w) {
    int tid = blockIdx.x * 256 + threadIdx.x;   // == tap*16384 + o*128 + c
    int c = tid & 127;
    int o = (tid >> 7) & 127;
    int tap = tid >> 14;
    g_wt[tid] = f2bf(w[(o * 128 + c) * 9 + tap]);
}

// Fills padded depth (interior + zero halo) and zeroes the x_t halo.
__global__ __launch_bounds__(256) void aux_fill(const float* __restrict__ depth) {
    int idx = blockIdx.x * 256 + threadIdx.x;
    if (idx < 135200) {                    // d_pad: 8*130*130
        int b = idx / 16900;
        int rem = idx - b * 16900;
        int hp = rem / 130;
        int wp = rem - hp * 130;
        float v = 0.f;
        if (hp >= 1 && hp <= 128 && wp >= 1 && wp <= 128)
            v = depth[b * 16384 + (hp - 1) * 128 + (wp - 1)];
        g_dp[idx] = v;
    } else if (idx < 135200 + 66048) {     // x_t halo: 8 * 516 pos * 16 units
        int u = idx - 135200;
        int b = u / 8256;
        int rem = u - b * 8256;
        int pos = rem >> 4;
        int unit = rem & 15;
        int hp, wp;
        if (pos < 130)      { hp = 0;           wp = pos; }
        else if (pos < 260) { hp = 129;         wp = pos - 130; }
        else if (pos < 388) { hp = pos - 259;   wp = 0; }
        else                { hp = pos - 387;   wp = 129; }
        size_t off = (((size_t)b * 130 + hp) * 130 + wp) * 128 + unit * 8;
        *reinterpret_cast<bf16x8*>(g_xt + off) = (bf16x8){0,0,0,0,0,0,0,0};
    }
}

// CHW fp32 -> HWC bf16 (interior). One 16B write per thread, coalesced
// (low 4 tid bits = c-octet).
__global__ __launch_bounds__(256) void x_transpose(const float* __restrict__ x) {
    int g = blockIdx.x * 256 + threadIdx.x;
    int oct = g & 15;
    int w = (g >> 4) & 127;
    int h = (g >> 11) & 127;
    int b = g >> 18;
    const float* p = x + ((size_t)(b * 128 + oct * 8)) * 16384 + h * 128 + w;
    bf16x8 pk;
    #pragma unroll
    for (int i = 0; i < 8; ++i)
        pk[i] = f2bf(p[(size_t)i * 16384]);
    size_t off = (((size_t)b * 130 + h + 1) * 130 + w + 1) * 128 + oct * 8;
    *reinterpret_cast<bf16x8*>(g_xt + off) = pk;
}

// One block per (b, h, w-half). No LDS, no barriers: B-fragments load
// directly from HWC bf16 x_t (L1-resident across kw re-reads), A-fragments
// from g_wt (L2-resident). Per tap: P = W_t * X_shift (MFMA), acc += sim*P.
__global__ __launch_bounds__(256) void depthconv_main(
    const float* __restrict__ bias, float* __restrict__ out)
{
    const int blk = blockIdx.x;
    const int b = blk >> 8;
    const int rem = blk & 255;
    const int h = rem >> 1;
    const int w0 = (rem & 1) << 6;

    const int tid = threadIdx.x;
    const int lane = tid & 63;
    const int wid = tid >> 6;
    const int l15 = lane & 15;
    const int khi = lane >> 4;
    const int obase = wid << 5;

    f32x4 acc[2][4];
    #pragma unroll
    for (int i = 0; i < 2; ++i)
        #pragma unroll
        for (int j = 0; j < 4; ++j)
            acc[i][j] = (f32x4){0.f, 0.f, 0.f, 0.f};

    const float* dpb = g_dp + b * 16900;
    float dc[4];
    #pragma unroll
    for (int j = 0; j < 4; ++j)
        dc[j] = dpb[(h + 1) * 130 + w0 + j * 16 + l15 + 1];

    for (int r = 0; r < 3; ++r) {
        #pragma unroll
        for (int kw = 0; kw < 3; ++kw) {
            const short* wtap = g_wt + (r * 3 + kw) * 16384;
            const short* xrow = g_xt + (((size_t)b * 130 + h + r) * 130 + w0 + kw) * 128;
            const float* drow = dpb + (h + r) * 130 + w0 + kw;

            float sim[4];
            #pragma unroll
            for (int j = 0; j < 4; ++j) {
                float dsv = drow[j * 16 + l15];
                sim[j] = __expf(-ALPHA * fabsf(dc[j] - dsv));
            }

            f32x4 P[2][4];
            #pragma unroll
            for (int i = 0; i < 2; ++i)
                #pragma unroll
                for (int j = 0; j < 4; ++j)
                    P[i][j] = (f32x4){0.f, 0.f, 0.f, 0.f};

            #pragma unroll
            for (int ks = 0; ks < 4; ++ks) {
                const int cb = ks * 32 + (khi << 3);
                bf16x8 afr[2], bfr[4];
                #pragma unroll
                for (int i = 0; i < 2; ++i) {
                    int orow = obase + i * 16 + l15;
                    afr[i] = *reinterpret_cast<const bf16x8*>(wtap + orow * 128 + cb);
                }
                #pragma unroll
                for (int j = 0; j < 4; ++j)
                    bfr[j] = *reinterpret_cast<const bf16x8*>(
                        xrow + (j * 16 + l15) * 128 + cb);
                #pragma unroll
                for (int i = 0; i < 2; ++i)
                    #pragma unroll
                    for (int j = 0; j < 4; ++j)
                        P[i][j] = __builtin_amdgcn_mfma_f32_16x16x32_bf16(
                            afr[i], bfr[j], P[i][j], 0, 0, 0);
            }

            #pragma unroll
            for (int j = 0; j < 4; ++j) {
                float sv = sim[j];
                #pragma unroll
                for (int i = 0; i < 2; ++i)
                    #pragma unroll
                    for (int rr = 0; rr < 4; ++rr)
                        acc[i][j][rr] += sv * P[i][j][rr];
            }
        }
    }

    // ---- epilogue: out[b][o][h][w0+wo] = acc + bias[o]
    #pragma unroll
    for (int i = 0; i < 2; ++i) {
        #pragma unroll
        for (int rr = 0; rr < 4; ++rr) {
            const int o = obase + i * 16 + (khi << 2) + rr;
            const float bv = bias[o];
            float* orow = out + (((size_t)(b * 128 + o)) * 128 + h) * 128 + w0;
            #pragma unroll
            for (int j = 0; j < 4; ++j)
                orow[j * 16 + l15] = acc[i][j][rr] + bv;
        }
    }
}

extern "C" void kernel_launch(void* const* d_in, const int* in_sizes, int n_in,
                              void* d_out, int out_size, void* d_ws, size_t ws_size,
                              hipStream_t stream) {
    const float* x     = (const float*)d_in[0];
    const float* depth = (const float*)d_in[1];
    const float* wgt   = (const float*)d_in[2];
    const float* bias  = (const float*)d_in[3];
    float* out = (float*)d_out;

    hipLaunchKernelGGL(wt_transform, dim3(576), dim3(256), 0, stream, wgt);
    hipLaunchKernelGGL(aux_fill, dim3(787), dim3(256), 0, stream, depth);
    hipLaunchKernelGGL(x_transpose, dim3(8192), dim3(256), 0, stream, x);
    hipLaunchKernelGGL(depthconv_main, dim3(8 * 128 * 2), dim3(256), 0, stream,
                       bias, out);
}

// Round 5
// 205.360 us; speedup vs baseline: 1.7845x; 1.7845x over previous
//
#include <hip/hip_runtime.h>
#include <hip/hip_bf16.h>
#include <cstdint>

#define ALPHA 8.3f

typedef __attribute__((ext_vector_type(8))) short bf16x8;
typedef __attribute__((ext_vector_type(4))) float f32x4;
typedef unsigned int u32;

// bf16 weights, layout [tap][o][c]  (9*128*128)
__device__ __align__(16) short g_wt[9 * 128 * 128];
// bf16 input, HWC with zero halo: [b][h'][w'][c], h',w' in [0,130)
__device__ __align__(16) short g_xt[(size_t)8 * 130 * 130 * 128];
// padded fp32 depth: [b][h'][w']
__device__ float g_dp[8 * 130 * 130];

__device__ __forceinline__ short f2bf(float f) {
    union { float f; uint32_t u; } v; v.f = f;
    uint32_t r = v.u + 0x7fffu + ((v.u >> 16) & 1u);
    return (short)(r >> 16);
}

// Fused prep: weight transform + padded depth + x_t halo zero.
__global__ __launch_bounds__(256) void prep(const float* __restrict__ w,
                                            const float* __restrict__ depth) {
    int idx = blockIdx.x * 256 + threadIdx.x;
    if (idx < 147456) {                       // g_wt[tap][o][c]
        int c = idx & 127, o = (idx >> 7) & 127, tap = idx >> 14;
        g_wt[idx] = f2bf(w[(o * 128 + c) * 9 + tap]);
    } else if (idx < 147456 + 135200) {       // g_dp: 8*130*130
        int u = idx - 147456;
        int b = u / 16900; int rem = u - b * 16900;
        int hp = rem / 130, wp = rem - hp * 130;
        float v = 0.f;
        if (hp >= 1 && hp <= 128 && wp >= 1 && wp <= 128)
            v = depth[b * 16384 + (hp - 1) * 128 + (wp - 1)];
        g_dp[u] = v;
    } else if (idx < 147456 + 135200 + 66048) {  // x_t halo: 8 * 516 pos * 16
        int u = idx - (147456 + 135200);
        int b = u / 8256; int rem = u - b * 8256;
        int pos = rem >> 4, unit = rem & 15;
        int hp, wp;
        if (pos < 130)      { hp = 0;         wp = pos; }
        else if (pos < 260) { hp = 129;       wp = pos - 130; }
        else if (pos < 388) { hp = pos - 259; wp = 0; }
        else                { hp = pos - 387; wp = 129; }
        size_t off = (((size_t)b * 130 + hp) * 130 + wp) * 128 + unit * 8;
        *reinterpret_cast<bf16x8*>(g_xt + off) = (bf16x8){0,0,0,0,0,0,0,0};
    }
}

// CHW fp32 -> HWC bf16 via LDS tile. Block = one (b,h).
// Phase 1: coalesced fp32 reads (lane = w), bf16 scalar writes into swizzled
// LDS [w][c] (2-way bank alias only). Phase 2: conflict-free b128 reads,
// coalesced 16B global writes.
__global__ __launch_bounds__(256) void x_transpose(const float* __restrict__ x) {
    __shared__ __align__(16) short T[128 * 128];   // 32 KB, [w][c] swizzled
    const int b = blockIdx.x >> 7;
    const int h = blockIdx.x & 127;
    const int tid = threadIdx.x;
    char* tp = (char*)T;

    const int w = tid & 127;
    const int c0 = tid >> 7;                        // 0..1
    const float* xb = x + (size_t)b * (128 * 16384) + h * 128 + w;
    #pragma unroll
    for (int i = 0; i < 64; ++i) {
        int c = c0 + i * 2;
        float v = xb[(size_t)c * 16384];
        int byte = (w << 8) | ((c << 1) ^ ((w & 15) << 4));
        *reinterpret_cast<short*>(tp + byte) = f2bf(v);
    }
    __syncthreads();

    size_t obase = (((size_t)b * 130 + h + 1) * 130 + 1) * 128;
    #pragma unroll
    for (int iter = 0; iter < 8; ++iter) {
        int idx = tid + iter * 256;
        int oct = idx & 15;
        int ww = idx >> 4;
        int byte = (ww << 8) | ((oct << 4) ^ ((ww & 15) << 4));
        bf16x8 v = *reinterpret_cast<const bf16x8*>(tp + byte);
        *reinterpret_cast<bf16x8*>(g_xt + obase + (size_t)ww * 128 + oct * 8) = v;
    }
}

// Block = (b, h-pair, w-half): out[b][0:128][h0:h0+2][w0:w0+64].
// Stage 4 input rows x 66 w (bf16 HWC) into LDS ONCE via global_load_lds
// (source pre-swizzled so ds_read_b128 is conflict-free), one barrier,
// then 9 taps of {L2 weight loads + LDS reads + MFMA} + sim-scaled fma.
// Wave wid: o-half = wid&1 (64 o), output row = h0 + (wid>>1).
__global__ __launch_bounds__(256, 2) void depthconv_main(
    const float* __restrict__ bias, float* __restrict__ out)
{
    __shared__ __align__(16) short Xs[264 * 128];   // 67584 B
    __shared__ float simL[9][2][64];                // 4608 B

    const int blk = blockIdx.x;
    const int b = blk >> 7;
    const int rem = blk & 127;
    const int h0 = (rem >> 1) << 1;
    const int w0 = (rem & 1) << 6;

    const int tid = threadIdx.x;
    const int lane = tid & 63;
    const int wid = tid >> 6;
    char* xsp = (char*)Xs;

    // ---- stage: 264 rows (4 input rows x 66 w) x 256 B, linear LDS dest,
    // source address carries the inverse XOR swizzle.
    const char* xtb = (const char*)g_xt +
        (((size_t)b * 130 + h0) * 130 + w0) * 256;
    #pragma unroll
    for (int iter = 0; iter < 17; ++iter) {
        int it = tid + iter * 256;
        if (it < 4224) {                    // wave-uniform (4224 % 64 == 0)
            int row = it >> 4;
            int c16 = (it & 15) ^ (row & 15);
            int r4 = row / 66;
            int wl = row - r4 * 66;
            const char* src = xtb + ((size_t)(r4 * 130 + wl)) * 256 + (c16 << 4);
            __builtin_amdgcn_global_load_lds(
                (const __attribute__((address_space(1))) u32*)src,
                (__attribute__((address_space(3))) u32*)(xsp + it * 16),
                16, 0, 0);
        }
    }

    // ---- sim table (overlaps staging latency): simL[tap][hsel][wo]
    const float* dpb = g_dp + b * 16900;
    #pragma unroll
    for (int iter = 0; iter < 5; ++iter) {
        int idx = tid + iter * 256;
        if (idx < 1152) {                   // wave-uniform (1152 % 64 == 0)
            int t = idx >> 7;
            int r2 = idx & 127;
            int hsel = r2 >> 6;
            int wo = r2 & 63;
            int kh = t / 3, kw = t - 3 * kh;
            int ho = h0 + hsel;
            float dc  = dpb[(ho + 1) * 130 + w0 + wo + 1];
            float dsv = dpb[(ho + kh) * 130 + w0 + wo + kw];
            simL[t][hsel][wo] = __expf(-ALPHA * fabsf(dc - dsv));
        }
    }
    __syncthreads();

    const int l15 = lane & 15;
    const int khi = lane >> 4;
    const int wo2 = wid & 1;
    const int hsel = wid >> 1;
    const int obase = wo2 << 6;

    f32x4 acc[4][4];
    #pragma unroll
    for (int i = 0; i < 4; ++i)
        #pragma unroll
        for (int j = 0; j < 4; ++j)
            acc[i][j] = (f32x4){0.f, 0.f, 0.f, 0.f};

    #pragma unroll
    for (int r = 0; r < 3; ++r) {
        #pragma unroll
        for (int kw = 0; kw < 3; ++kw) {
            const int tap = r * 3 + kw;
            const short* wtap = g_wt + tap * 16384;

            float sim[4];
            #pragma unroll
            for (int j = 0; j < 4; ++j)
                sim[j] = simL[tap][hsel][j * 16 + l15];

            f32x4 P[4][4];
            #pragma unroll
            for (int i = 0; i < 4; ++i)
                #pragma unroll
                for (int j = 0; j < 4; ++j)
                    P[i][j] = (f32x4){0.f, 0.f, 0.f, 0.f};

            #pragma unroll
            for (int ks = 0; ks < 4; ++ks) {
                const int cb = ks * 32 + (khi << 3);
                bf16x8 afr[4], bfr[4];
                #pragma unroll
                for (int i = 0; i < 4; ++i)
                    afr[i] = *reinterpret_cast<const bf16x8*>(
                        wtap + (obase + i * 16 + l15) * 128 + cb);
                #pragma unroll
                for (int j = 0; j < 4; ++j) {
                    int row = (hsel + r) * 66 + j * 16 + l15 + kw;
                    int byte = (row << 8) | ((cb << 1) ^ ((row & 15) << 4));
                    bfr[j] = *reinterpret_cast<const bf16x8*>(xsp + byte);
                }
                #pragma unroll
                for (int i = 0; i < 4; ++i)
                    #pragma unroll
                    for (int j = 0; j < 4; ++j)
                        P[i][j] = __builtin_amdgcn_mfma_f32_16x16x32_bf16(
                            afr[i], bfr[j], P[i][j], 0, 0, 0);
            }

            #pragma unroll
            for (int j = 0; j < 4; ++j) {
                float sv = sim[j];
                #pragma unroll
                for (int i = 0; i < 4; ++i)
                    #pragma unroll
                    for (int rr = 0; rr < 4; ++rr)
                        acc[i][j][rr] += sv * P[i][j][rr];
            }
        }
    }

    // ---- epilogue
    #pragma unroll
    for (int i = 0; i < 4; ++i) {
        #pragma unroll
        for (int rr = 0; rr < 4; ++rr) {
            const int o = obase + i * 16 + (khi << 2) + rr;
            const float bv = bias[o];
            float* orow = out + (((size_t)(b * 128 + o)) * 128 + (h0 + hsel)) * 128 + w0;
            #pragma unroll
            for (int j = 0; j < 4; ++j)
                orow[j * 16 + l15] = acc[i][j][rr] + bv;
        }
    }
}

extern "C" void kernel_launch(void* const* d_in, const int* in_sizes, int n_in,
                              void* d_out, int out_size, void* d_ws, size_t ws_size,
                              hipStream_t stream) {
    const float* x     = (const float*)d_in[0];
    const float* depth = (const float*)d_in[1];
    const float* wgt   = (const float*)d_in[2];
    const float* bias  = (const float*)d_in[3];
    float* out = (float*)d_out;

    hipLaunchKernelGGL(prep, dim3(1363), dim3(256), 0, stream, wgt, depth);
    hipLaunchKernelGGL(x_transpose, dim3(8 * 128), dim3(256), 0, stream, x);
    hipLaunchKernelGGL(depthconv_main, dim3(8 * 64 * 2), dim3(256), 0, stream,
                       bias, out);
}